// Round 1
// baseline (8867.625 us; speedup 1.0000x reference)
//
#include <hip/hip_runtime.h>
#include <cmath>
#include <cstdint>

#define D_FEAT 6
#define T_SEQ  60
#define HID    256
#define G3     768
#define NROW   2048
#define NSAMP  20480

__device__ __forceinline__ float sigmoidf_(float x) { return 1.0f / (1.0f + expf(-x)); }

// ---------------------------------------------------------------- weight prep
struct PrepArgs {
  const float* src[8];
  float* dst[8];
  int N[8], K[8], ro[8];
};

__global__ void prep_weights(PrepArgs a) {
  int seg = blockIdx.y;
  const float* S = a.src[seg];
  float* D = a.dst[seg];
  int N = a.N[seg], K = a.K[seg], ro = a.ro[seg];
  int total = N * K;
  for (int i = blockIdx.x * blockDim.x + threadIdx.x; i < total; i += gridDim.x * blockDim.x) {
    int n = i / K, k = i - n * K;
    D[(size_t)(k + ro) * N + n] = S[i];   // WT[k][n] = W[n][k]
  }
}

// ---------------------------------------------------------------- GRU layer 0 step
// gh = h_prev @ W_hh0^T (K=256), xw = x_t @ W_ih0^T (K=6, from inp), fused gates.
__global__ __launch_bounds__(256, 2)
void gru0_step(const float* __restrict__ hprev, float* __restrict__ hout,
               const float* __restrict__ inp, const float* __restrict__ WT_hh,
               const float* __restrict__ Wih, const float* __restrict__ bih,
               const float* __restrict__ bhh, int t)
{
  __shared__ float4 As4[64 * 32];   // [k4][m], 32 rows of h_prev
  __shared__ float xs[32][6];
  const int tx = threadIdx.x, ty = threadIdx.y;
  const int tid = ty * 32 + tx;
  const int j0 = blockIdx.x * 32, m0 = blockIdx.y * 32;

  for (int c = tid; c < 2048; c += 256) {
    int k4 = c & 63, m = c >> 6;
    As4[k4 * 32 + m] = *(const float4*)(hprev + (size_t)(m0 + m) * HID + k4 * 4);
  }
  if (tid < 192) {
    int m = tid / 6, i = tid - m * 6;
    xs[m][i] = inp[(size_t)(m0 + m) * (D_FEAT * T_SEQ) + i * T_SEQ + t];
  }
  __syncthreads();

  float acc[4][3];
#pragma unroll
  for (int r = 0; r < 4; ++r)
#pragma unroll
    for (int g = 0; g < 3; ++g) acc[r][g] = 0.f;

  const int j = j0 + tx;
  const float* Wb = WT_hh + j;
  for (int k4 = 0; k4 < 64; ++k4) {
    float4 a0 = As4[k4 * 32 + ty * 4 + 0];
    float4 a1 = As4[k4 * 32 + ty * 4 + 1];
    float4 a2 = As4[k4 * 32 + ty * 4 + 2];
    float4 a3 = As4[k4 * 32 + ty * 4 + 3];
    const float* pb = Wb + (size_t)k4 * 4 * G3;
#pragma unroll
    for (int kk = 0; kk < 4; ++kk) {
      float br = pb[kk * G3];
      float bz = pb[kk * G3 + 256];
      float bn = pb[kk * G3 + 512];
      float e0 = ((const float*)&a0)[kk];
      float e1 = ((const float*)&a1)[kk];
      float e2 = ((const float*)&a2)[kk];
      float e3 = ((const float*)&a3)[kk];
      acc[0][0] += e0 * br; acc[0][1] += e0 * bz; acc[0][2] += e0 * bn;
      acc[1][0] += e1 * br; acc[1][1] += e1 * bz; acc[1][2] += e1 * bn;
      acc[2][0] += e2 * br; acc[2][1] += e2 * bz; acc[2][2] += e2 * bn;
      acc[3][0] += e3 * br; acc[3][1] += e3 * bz; acc[3][2] += e3 * bn;
    }
  }

#pragma unroll
  for (int r = 0; r < 4; ++r) {
    int row = m0 + ty * 4 + r;
    float xw[3];
#pragma unroll
    for (int g = 0; g < 3; ++g) {
      const float* wi = Wih + (size_t)(g * 256 + j) * D_FEAT;
      float s = bih[g * 256 + j];
#pragma unroll
      for (int i = 0; i < D_FEAT; ++i) s += xs[ty * 4 + r][i] * wi[i];
      xw[g] = s;
    }
    float ghr = acc[r][0] + bhh[j];
    float ghz = acc[r][1] + bhh[256 + j];
    float ghn = acc[r][2] + bhh[512 + j];
    float rr = sigmoidf_(xw[0] + ghr);
    float zz = sigmoidf_(xw[1] + ghz);
    float nn = tanhf(xw[2] + rr * ghn);
    float hold = hprev[(size_t)row * HID + j];
    hout[(size_t)row * HID + j] = (1.f - zz) * nn + zz * hold;
  }
}

// ---------------------------------------------------------------- GRU layer 1 step
// Concatenated K=512 GEMM: [x_t | h_prev] @ [W_ih1 ; W_hh1]^T, fused gates.
__global__ __launch_bounds__(256, 2)
void gru1_step(const float* __restrict__ xin, const float* __restrict__ hprev,
               float* __restrict__ hout, const float* __restrict__ WTcat,
               const float* __restrict__ bih, const float* __restrict__ bhh)
{
  __shared__ float4 As4[128 * 32];   // [k4][m], k<256 -> xin, k>=256 -> hprev
  const int tx = threadIdx.x, ty = threadIdx.y;
  const int tid = ty * 32 + tx;
  const int j0 = blockIdx.x * 32, m0 = blockIdx.y * 32;

  for (int c = tid; c < 4096; c += 256) {
    int k4 = c & 127, m = c >> 7;
    const float* src = (k4 < 64) ? (xin + (size_t)(m0 + m) * HID + k4 * 4)
                                 : (hprev + (size_t)(m0 + m) * HID + (k4 - 64) * 4);
    As4[k4 * 32 + m] = *(const float4*)src;
  }
  __syncthreads();

  float ar[4] = {0,0,0,0}, az[4] = {0,0,0,0}, axn[4] = {0,0,0,0}, ahn[4] = {0,0,0,0};
  const int j = j0 + tx;
  const float* Wb = WTcat + j;

  for (int k4 = 0; k4 < 64; ++k4) {
    float4 a0 = As4[k4 * 32 + ty * 4 + 0];
    float4 a1 = As4[k4 * 32 + ty * 4 + 1];
    float4 a2 = As4[k4 * 32 + ty * 4 + 2];
    float4 a3 = As4[k4 * 32 + ty * 4 + 3];
    const float* pb = Wb + (size_t)k4 * 4 * G3;
#pragma unroll
    for (int kk = 0; kk < 4; ++kk) {
      float br = pb[kk * G3];
      float bz = pb[kk * G3 + 256];
      float bn = pb[kk * G3 + 512];
      float e0 = ((const float*)&a0)[kk];
      float e1 = ((const float*)&a1)[kk];
      float e2 = ((const float*)&a2)[kk];
      float e3 = ((const float*)&a3)[kk];
      ar[0] += e0 * br; az[0] += e0 * bz; axn[0] += e0 * bn;
      ar[1] += e1 * br; az[1] += e1 * bz; axn[1] += e1 * bn;
      ar[2] += e2 * br; az[2] += e2 * bz; axn[2] += e2 * bn;
      ar[3] += e3 * br; az[3] += e3 * bz; axn[3] += e3 * bn;
    }
  }
  for (int k4 = 64; k4 < 128; ++k4) {
    float4 a0 = As4[k4 * 32 + ty * 4 + 0];
    float4 a1 = As4[k4 * 32 + ty * 4 + 1];
    float4 a2 = As4[k4 * 32 + ty * 4 + 2];
    float4 a3 = As4[k4 * 32 + ty * 4 + 3];
    const float* pb = Wb + (size_t)k4 * 4 * G3;
#pragma unroll
    for (int kk = 0; kk < 4; ++kk) {
      float br = pb[kk * G3];
      float bz = pb[kk * G3 + 256];
      float bn = pb[kk * G3 + 512];
      float e0 = ((const float*)&a0)[kk];
      float e1 = ((const float*)&a1)[kk];
      float e2 = ((const float*)&a2)[kk];
      float e3 = ((const float*)&a3)[kk];
      ar[0] += e0 * br; az[0] += e0 * bz; ahn[0] += e0 * bn;
      ar[1] += e1 * br; az[1] += e1 * bz; ahn[1] += e1 * bn;
      ar[2] += e2 * br; az[2] += e2 * bz; ahn[2] += e2 * bn;
      ar[3] += e3 * br; az[3] += e3 * bz; ahn[3] += e3 * bn;
    }
  }

#pragma unroll
  for (int r = 0; r < 4; ++r) {
    int row = m0 + ty * 4 + r;
    float rr = sigmoidf_(ar[r] + bih[j] + bhh[j]);
    float zz = sigmoidf_(az[r] + bih[256 + j] + bhh[256 + j]);
    float nn = tanhf((axn[r] + bih[512 + j]) + rr * (ahn[r] + bhh[512 + j]));
    float hold = hprev[(size_t)row * HID + j];
    hout[(size_t)row * HID + j] = (1.f - zz) * nn + zz * hold;
  }
}

// ---------------------------------------------------------------- generic GEMM
// C[M,N] = act(A @ WT + bias), WT layout [k][n]. Optional row gather for A.
__global__ __launch_bounds__(256, 2)
void gemm_act(const float* __restrict__ A, const int* __restrict__ rowsrc,
              const float* __restrict__ WT, const float* __restrict__ bias,
              float* __restrict__ C, int M, int N, int K, int act)
{
  __shared__ float4 As4[128 * 32];
  const int tx = threadIdx.x, ty = threadIdx.y;
  const int tid = ty * 32 + tx;
  const int n0 = blockIdx.x * 32, m0 = blockIdx.y * 32;
  const int K4 = K >> 2;

  for (int c = tid; c < K4 * 32; c += 256) {
    int k4 = c % K4, m = c / K4;
    int row = m0 + m;
    if (rowsrc) row = rowsrc[row];
    As4[k4 * 32 + m] = *(const float4*)(A + (size_t)row * K + k4 * 4);
  }
  __syncthreads();

  float acc[4] = {0,0,0,0};
  const int n = n0 + tx;
  const float* pb = WT + n;
  for (int k4 = 0; k4 < K4; ++k4) {
    float4 a0 = As4[k4 * 32 + ty * 4 + 0];
    float4 a1 = As4[k4 * 32 + ty * 4 + 1];
    float4 a2 = As4[k4 * 32 + ty * 4 + 2];
    float4 a3 = As4[k4 * 32 + ty * 4 + 3];
#pragma unroll
    for (int kk = 0; kk < 4; ++kk) {
      float b = pb[(size_t)(k4 * 4 + kk) * N];
      acc[0] += ((const float*)&a0)[kk] * b;
      acc[1] += ((const float*)&a1)[kk] * b;
      acc[2] += ((const float*)&a2)[kk] * b;
      acc[3] += ((const float*)&a3)[kk] * b;
    }
  }
  float bb = bias ? bias[n] : 0.f;
#pragma unroll
  for (int r = 0; r < 4; ++r) {
    float v = acc[r] + bb;
    if (act) v = (v >= 0.f) ? v : 0.01f * v;
    C[(size_t)(m0 + ty * 4 + r) * N + n] = v;
  }
}

// ---------------------------------------------------------------- small stages
__global__ void mbday_kernel(const float* __restrict__ mb, float* __restrict__ mbday) {
  int d = blockIdx.x, c = threadIdx.x;
  float s = 0.f;
  for (int st = 0; st < 512; ++st) s += mb[(size_t)(d * 512 + st) * 256 + c];
  mbday[d * 256 + c] = s * (1.0f / 512.0f);
}

__global__ void daytopk_kernel(const float* __restrict__ mbday, const float* __restrict__ thd,
                               int* __restrict__ dayidx) {
  __shared__ float mbs[256];
  __shared__ float sim[256];
  __shared__ float red[256];
  __shared__ int   redi[256];
  const int d = blockIdx.x, t = threadIdx.x;
  mbs[t] = mbday[d * 256 + t];
  __syncthreads();
  red[t] = mbs[t] * mbs[t];
  __syncthreads();
  for (int o = 128; o; o >>= 1) { if (t < o) red[t] += red[t + o]; __syncthreads(); }
  float xn = sqrtf(red[0]);
  float v = -INFINITY;
  if (t < 240) {
    float dot = 0.f, yn2 = 0.f;
    for (int k = 0; k < 256; ++k) {
      float y = thd[t * 256 + k];
      dot += mbs[k] * y;
      yn2 += y * y;
    }
    float den = xn * sqrtf(yn2);
    v = (den > 0.f) ? dot / den : 0.f;
  }
  sim[t] = v;
  __syncthreads();
  for (int it = 0; it < 10; ++it) {
    red[t] = sim[t]; redi[t] = t;
    __syncthreads();
    for (int o = 128; o; o >>= 1) {
      if (t < o) {
        if (red[t + o] > red[t] || (red[t + o] == red[t] && redi[t + o] < redi[t])) {
          red[t] = red[t + o]; redi[t] = redi[t + o];
        }
      }
      __syncthreads();
    }
    if (t == 0) { int bi = redi[0]; dayidx[d * 10 + it] = bi; sim[bi] = -INFINITY; }
    __syncthreads();
  }
}

__global__ void rowsrc_kernel(const int* __restrict__ dayidx, int* __restrict__ rowsrc) {
  int r = blockIdx.x * 256 + threadIdx.x;
  if (r < NSAMP) rowsrc[r] = dayidx[r >> 9] * 512 + (r & 511);
}

__global__ void rownorm_kernel(const float* __restrict__ X, float* __restrict__ out, int rows) {
  int w = threadIdx.x >> 6;
  int lane = threadIdx.x & 63;
  int row = blockIdx.x * 4 + w;
  if (row >= rows) return;
  float4 x = *(const float4*)(X + (size_t)row * 256 + lane * 4);
  float s = x.x * x.x + x.y * x.y + x.z * x.z + x.w * x.w;
#pragma unroll
  for (int o = 32; o; o >>= 1) s += __shfl_down(s, o, 64);
  if (lane == 0) out[row] = sqrtf(s);
}

__global__ void qnorm_kernel(float* __restrict__ q, const float* __restrict__ qn) {
  int i = blockIdx.x * 256 + threadIdx.x;
  int row = i >> 8;
  float n = qn[row];
  q[i] = (n > 0.f) ? q[i] / n : 0.f;
}

__global__ void khT_kernel(const float* __restrict__ kh, const float* __restrict__ khn,
                           float* __restrict__ khT) {
  __shared__ float tile[32][33];
  int jb = blockIdx.x * 32;
  int kb = blockIdx.y * 32;
  int tx = threadIdx.x & 31, tyy = threadIdx.x >> 5;
  for (int rr = tyy; rr < 32; rr += 8) {
    float n = khn[jb + rr];
    float v = kh[(size_t)(jb + rr) * 256 + kb + tx];
    tile[rr][tx] = (n > 0.f) ? v / n : 0.f;
  }
  __syncthreads();
  for (int rr = tyy; rr < 32; rr += 8) {
    khT[(size_t)(kb + rr) * NSAMP + jb + tx] = tile[tx][rr];
  }
}

// ---------------------------------------------------------------- cs GEMM + top-10
__global__ __launch_bounds__(256)
void csmax_kernel(const float* __restrict__ qh, const float* __restrict__ khT,
                  float* __restrict__ topv, int* __restrict__ topi)
{
  __shared__ float4 qs[256][2];     // [k][0]: rows 0..3, [k][1]: rows 4..7
  __shared__ float csch[8 * 512];
  const int tid = threadIdx.x;
  const int m0 = blockIdx.x * 8;
  {
    int k = tid;
    float4 v0, v1;
    v0.x = qh[(size_t)(m0 + 0) * 256 + k]; v0.y = qh[(size_t)(m0 + 1) * 256 + k];
    v0.z = qh[(size_t)(m0 + 2) * 256 + k]; v0.w = qh[(size_t)(m0 + 3) * 256 + k];
    v1.x = qh[(size_t)(m0 + 4) * 256 + k]; v1.y = qh[(size_t)(m0 + 5) * 256 + k];
    v1.z = qh[(size_t)(m0 + 6) * 256 + k]; v1.w = qh[(size_t)(m0 + 7) * 256 + k];
    qs[k][0] = v0; qs[k][1] = v1;
  }
  __syncthreads();
  const int lane = tid & 63;
  const int wv = tid >> 6;

  float tv0[10], tv1[10];
  int   tj0[10], tj1[10];
  int   tn0 = 0, tn1 = 0;
  float tmv0 = -INFINITY, tmv1 = -INFINITY;
  int   tmi0 = 0, tmi1 = 0;

  auto process_row = [&](int r, float (&tv)[10], int (&tj)[10], int& tn,
                         float& tmv, int& tmi, int jb) {
    float4 c0 = *(const float4*)&csch[r * 512 + lane * 8];
    float4 c1 = *(const float4*)&csch[r * 512 + lane * 8 + 4];
    float cv[8] = {c0.x, c0.y, c0.z, c0.w, c1.x, c1.y, c1.z, c1.w};
    const int cj0 = jb + lane * 8;
    while (true) {
      float bv = -INFINITY; int bj = 0x7fffffff;
#pragma unroll
      for (int u = 0; u < 8; ++u) {
        if (cv[u] > bv) { bv = cv[u]; bj = cj0 + u; }
      }
#pragma unroll
      for (int o = 32; o; o >>= 1) {
        float ov = __shfl_down(bv, o, 64);
        int   oj = __shfl_down(bj, o, 64);
        if (ov > bv || (ov == bv && oj < bj)) { bv = ov; bj = oj; }
      }
      bv = __shfl(bv, 0, 64); bj = __shfl(bj, 0, 64);
      bool take;
      if (tn < 10) take = true;
      else take = (bv > tmv) || (bv == tmv && bj < tmi);
      if (!take) break;
      if (tn < 10) {
#pragma unroll
        for (int s = 0; s < 10; ++s) if (s == tn) { tv[s] = bv; tj[s] = bj; }
        tn++;
        if (tn == 10) {
          float mv = tv[0]; int mi = tj[0];
#pragma unroll
          for (int s = 1; s < 10; ++s) {
            bool w = (tv[s] < mv) || (tv[s] == mv && tj[s] > mi);
            if (w) { mv = tv[s]; mi = tj[s]; }
          }
          tmv = mv; tmi = mi;
        }
      } else {
        int ms = 0; float mv = tv[0]; int mi = tj[0];
#pragma unroll
        for (int s = 1; s < 10; ++s) {
          bool w = (tv[s] < mv) || (tv[s] == mv && tj[s] > mi);
          if (w) { ms = s; mv = tv[s]; mi = tj[s]; }
        }
#pragma unroll
        for (int s = 0; s < 10; ++s) if (s == ms) { tv[s] = bv; tj[s] = bj; }
        mv = tv[0]; mi = tj[0];
#pragma unroll
        for (int s = 1; s < 10; ++s) {
          bool w = (tv[s] < mv) || (tv[s] == mv && tj[s] > mi);
          if (w) { mv = tv[s]; mi = tj[s]; }
        }
        tmv = mv; tmi = mi;
      }
#pragma unroll
      for (int u = 0; u < 8; ++u) if (cj0 + u == bj) cv[u] = -INFINITY;
    }
  };

  for (int ch = 0; ch < 40; ++ch) {
    const int jb = ch * 512;
    float acc[8][2];
#pragma unroll
    for (int r = 0; r < 8; ++r) { acc[r][0] = 0.f; acc[r][1] = 0.f; }
    const float* kp = khT + jb + tid;
#pragma unroll 4
    for (int k = 0; k < 256; ++k) {
      float4 qa = qs[k][0];
      float4 qb = qs[k][1];
      float b0 = kp[(size_t)k * NSAMP];
      float b1 = kp[(size_t)k * NSAMP + 256];
      acc[0][0] += qa.x * b0; acc[1][0] += qa.y * b0; acc[2][0] += qa.z * b0; acc[3][0] += qa.w * b0;
      acc[4][0] += qb.x * b0; acc[5][0] += qb.y * b0; acc[6][0] += qb.z * b0; acc[7][0] += qb.w * b0;
      acc[0][1] += qa.x * b1; acc[1][1] += qa.y * b1; acc[2][1] += qa.z * b1; acc[3][1] += qa.w * b1;
      acc[4][1] += qb.x * b1; acc[5][1] += qb.y * b1; acc[6][1] += qb.z * b1; acc[7][1] += qb.w * b1;
    }
    __syncthreads();   // previous chunk's top-k reads of csch are done
#pragma unroll
    for (int r = 0; r < 8; ++r) {
      csch[r * 512 + tid] = acc[r][0];
      csch[r * 512 + 256 + tid] = acc[r][1];
    }
    __syncthreads();
    process_row(wv,     tv0, tj0, tn0, tmv0, tmi0, jb);
    process_row(wv + 4, tv1, tj1, tn1, tmv1, tmi1, jb);
  }
  __syncthreads();

  if (lane == 0) {
    int row0 = m0 + wv;
#pragma unroll
    for (int s = 0; s < 10; ++s) { topv[row0 * 10 + s] = tv0[s]; topi[row0 * 10 + s] = tj0[s]; }
    int row1 = m0 + wv + 4;
#pragma unroll
    for (int s = 0; s < 10; ++s) { topv[row1 * 10 + s] = tv1[s]; topi[row1 * 10 + s] = tj1[s]; }
  }
}

// ---------------------------------------------------------------- final: agg + fc
__global__ void final_kernel(const float* __restrict__ mb, const float* __restrict__ kh,
                             const float* __restrict__ topv, const int* __restrict__ topi,
                             const float* __restrict__ fcW, const float* __restrict__ fcb,
                             float* __restrict__ y)
{
  __shared__ float red[256];
  int n = blockIdx.x, c = threadIdx.x;
  float agg = 0.f;
#pragma unroll
  for (int k = 0; k < 10; ++k) {
    float w = topv[n * 10 + k] / 10.0f;
    int idx = topi[n * 10 + k];
    agg += w * kh[(size_t)idx * 256 + c];
  }
  float val = fcW[c] * mb[(size_t)n * 256 + c] + fcW[256 + c] * agg;
  red[c] = val;
  __syncthreads();
  for (int o = 128; o; o >>= 1) { if (c < o) red[c] += red[c + o]; __syncthreads(); }
  if (c == 0) y[n] = red[0] + fcb[0];
}

// ---------------------------------------------------------------- launch
extern "C" void kernel_launch(void* const* d_in, const int* in_sizes, int n_in,
                              void* d_out, int out_size, void* d_ws, size_t ws_size,
                              hipStream_t stream)
{
  const float* inp    = (const float*)d_in[0];
  const float* trainh = (const float*)d_in[1];
  const float* thd    = (const float*)d_in[2];
  const float* Wih0   = (const float*)d_in[3];
  const float* Whh0   = (const float*)d_in[4];
  const float* bih0   = (const float*)d_in[5];
  const float* bhh0   = (const float*)d_in[6];
  const float* Wih1   = (const float*)d_in[7];
  const float* Whh1   = (const float*)d_in[8];
  const float* bih1   = (const float*)d_in[9];
  const float* bhh1   = (const float*)d_in[10];
  const float* lin0W  = (const float*)d_in[11];
  const float* lin0b  = (const float*)d_in[12];
  const float* lin1W  = (const float*)d_in[13];
  const float* lin1b  = (const float*)d_in[14];
  const float* lin2W  = (const float*)d_in[15];
  const float* lin2b  = (const float*)d_in[16];
  const float* p1W    = (const float*)d_in[17];
  const float* p2W    = (const float*)d_in[18];
  const float* fcW    = (const float*)d_in[19];
  const float* fcb    = (const float*)d_in[20];

  float* ws = (float*)d_ws;
  // workspace map (floats) — total ~17.06M floats ≈ 68.3 MB
  float* WT_hh0 = ws + 0;          // 256x768
  float* WTcat  = ws + 196608;     // 512x768
  float* WT_l0  = ws + 589824;     // 256x512
  float* WT_l1  = ws + 720896;     // 512x512
  float* WT_l2  = ws + 983040;     // 512x256
  float* WT_p1  = ws + 1114112;    // 256x256
  float* WT_p2  = ws + 1179648;    // 256x256
  float* h0a    = ws + 1245184;
  float* h0b    = ws + 1769472;
  float* h1a    = ws + 2293760;
  float* h1b    = ws + 2818048;
  float* mb1    = ws + 3342336;    // 2048x512
  float* mb2    = ws + 4390912;    // 2048x512
  float* mbf    = ws + 5439488;    // 2048x256
  float* mbday  = ws + 5963776;    // 4x256
  float* qbuf   = ws + 5964800;    // 2048x256
  float* kh     = ws + 6489088;    // 20480x256
  float* khT    = ws + 11731968;   // 256x20480 (normalized)
  float* khn    = ws + 16974848;   // 20480
  float* qn     = ws + 16995328;   // 2048
  float* topv   = ws + 16997376;   // 2048x10
  int*   dayidx = (int*)(ws + 17017856); // 40
  int*   rowsrc = (int*)(ws + 17017920); // 20480
  int*   topi   = (int*)(ws + 17038400); // 2048x10

  PrepArgs pa;
  pa.src[0] = Whh0;  pa.dst[0] = WT_hh0; pa.N[0] = 768; pa.K[0] = 256; pa.ro[0] = 0;
  pa.src[1] = Wih1;  pa.dst[1] = WTcat;  pa.N[1] = 768; pa.K[1] = 256; pa.ro[1] = 0;
  pa.src[2] = Whh1;  pa.dst[2] = WTcat;  pa.N[2] = 768; pa.K[2] = 256; pa.ro[2] = 256;
  pa.src[3] = lin0W; pa.dst[3] = WT_l0;  pa.N[3] = 512; pa.K[3] = 256; pa.ro[3] = 0;
  pa.src[4] = lin1W; pa.dst[4] = WT_l1;  pa.N[4] = 512; pa.K[4] = 512; pa.ro[4] = 0;
  pa.src[5] = lin2W; pa.dst[5] = WT_l2;  pa.N[5] = 256; pa.K[5] = 512; pa.ro[5] = 0;
  pa.src[6] = p1W;   pa.dst[6] = WT_p1;  pa.N[6] = 256; pa.K[6] = 256; pa.ro[6] = 0;
  pa.src[7] = p2W;   pa.dst[7] = WT_p2;  pa.N[7] = 256; pa.K[7] = 256; pa.ro[7] = 0;
  prep_weights<<<dim3(64, 8), dim3(256), 0, stream>>>(pa);

  hipMemsetAsync(h0a, 0, (size_t)NROW * HID * 4, stream);
  hipMemsetAsync(h1a, 0, (size_t)NROW * HID * 4, stream);

  float *h0c = h0a, *h0n = h0b, *h1c = h1a, *h1n = h1b;
  for (int t = 0; t < T_SEQ; ++t) {
    gru0_step<<<dim3(8, 64), dim3(32, 8), 0, stream>>>(h0c, h0n, inp, WT_hh0, Wih0, bih0, bhh0, t);
    gru1_step<<<dim3(8, 64), dim3(32, 8), 0, stream>>>(h0n, h1c, h1n, WTcat, bih1, bhh1);
    float* tmp;
    tmp = h0c; h0c = h0n; h0n = tmp;
    tmp = h1c; h1c = h1n; h1n = tmp;
  }

  gemm_act<<<dim3(16, 64), dim3(32, 8), 0, stream>>>(h1c, nullptr, WT_l0, lin0b, mb1, 2048, 512, 256, 1);
  gemm_act<<<dim3(16, 64), dim3(32, 8), 0, stream>>>(mb1, nullptr, WT_l1, lin1b, mb2, 2048, 512, 512, 1);
  gemm_act<<<dim3(8, 64),  dim3(32, 8), 0, stream>>>(mb2, nullptr, WT_l2, lin2b, mbf, 2048, 256, 512, 1);

  mbday_kernel<<<4, 256, 0, stream>>>(mbf, mbday);
  daytopk_kernel<<<4, 256, 0, stream>>>(mbday, thd, dayidx);
  rowsrc_kernel<<<80, 256, 0, stream>>>(dayidx, rowsrc);

  gemm_act<<<dim3(8, 640), dim3(32, 8), 0, stream>>>(trainh, rowsrc, WT_p2, nullptr, kh, 20480, 256, 256, 0);
  gemm_act<<<dim3(8, 64),  dim3(32, 8), 0, stream>>>(mbf, nullptr, WT_p1, nullptr, qbuf, 2048, 256, 256, 0);

  rownorm_kernel<<<5120, 256, 0, stream>>>(kh, khn, 20480);
  rownorm_kernel<<<512, 256, 0, stream>>>(qbuf, qn, 2048);
  qnorm_kernel<<<2048, 256, 0, stream>>>(qbuf, qn);
  khT_kernel<<<dim3(640, 8), 256, 0, stream>>>(kh, khn, khT);

  csmax_kernel<<<256, 256, 0, stream>>>(qbuf, khT, topv, topi);
  final_kernel<<<2048, 256, 0, stream>>>(mbf, kh, topv, topi, fcW, fcb, (float*)d_out);

  (void)in_sizes; (void)n_in; (void)out_size; (void)ws_size;
}

// Round 2
// 5781.245 us; speedup vs baseline: 1.5339x; 1.5339x over previous
//
#include <hip/hip_runtime.h>
#include <cmath>
#include <cstdint>

#define D_FEAT 6
#define T_SEQ  60
#define HID    256
#define G3     768
#define NROW   2048
#define NSAMP  20480

__device__ __forceinline__ float sigmoidf_(float x) { return 1.0f / (1.0f + expf(-x)); }

// ---------------------------------------------------------------- weight prep
struct PrepArgs {
  const float* src[8];
  float* dst[8];
  int N[8], K[8], ro[8];
};

__global__ void prep_weights(PrepArgs a) {
  int seg = blockIdx.y;
  const float* S = a.src[seg];
  float* D = a.dst[seg];
  int N = a.N[seg], K = a.K[seg], ro = a.ro[seg];
  int total = N * K;
  for (int i = blockIdx.x * blockDim.x + threadIdx.x; i < total; i += gridDim.x * blockDim.x) {
    int n = i / K, k = i - n * K;
    D[(size_t)(k + ro) * N + n] = S[i];   // WT[k][n] = W[n][k]
  }
}

// ---------------------------------------------------------------- GRU layer 0 step
__global__ __launch_bounds__(256, 2)
void gru0_step(const float* __restrict__ hprev, float* __restrict__ hout,
               const float* __restrict__ inp, const float* __restrict__ WT_hh,
               const float* __restrict__ Wih, const float* __restrict__ bih,
               const float* __restrict__ bhh, int t)
{
  __shared__ float4 As4[64 * 32];   // [k4][m]
  __shared__ float xs[32][6];
  const int tx = threadIdx.x, ty = threadIdx.y;
  const int tid = ty * 32 + tx;
  const int j0 = blockIdx.x * 32, m0 = blockIdx.y * 32;

  for (int c = tid; c < 2048; c += 256) {
    int k4 = c & 63, m = c >> 6;
    As4[k4 * 32 + m] = *(const float4*)(hprev + (size_t)(m0 + m) * HID + k4 * 4);
  }
  if (tid < 192) {
    int m = tid / 6, i = tid - m * 6;
    xs[m][i] = inp[(size_t)(m0 + m) * (D_FEAT * T_SEQ) + i * T_SEQ + t];
  }
  __syncthreads();

  float acc[4][3];
#pragma unroll
  for (int r = 0; r < 4; ++r)
#pragma unroll
    for (int g = 0; g < 3; ++g) acc[r][g] = 0.f;

  const int j = j0 + tx;
  const float* Wb = WT_hh + j;

  // software pipeline: prefetch next k4's 12 B-values while FMA-ing current
  float bc[12], bn_[12];
#pragma unroll
  for (int kk = 0; kk < 4; ++kk) {
    bc[kk*3+0] = Wb[(size_t)kk * G3];
    bc[kk*3+1] = Wb[(size_t)kk * G3 + 256];
    bc[kk*3+2] = Wb[(size_t)kk * G3 + 512];
  }
  for (int k4 = 0; k4 < 64; ++k4) {
    int nk4 = (k4 + 1) & 63;            // wrap: last prefetch reads row 0 (unused)
    const float* pn = Wb + (size_t)nk4 * 4 * G3;
#pragma unroll
    for (int kk = 0; kk < 4; ++kk) {
      bn_[kk*3+0] = pn[kk * G3];
      bn_[kk*3+1] = pn[kk * G3 + 256];
      bn_[kk*3+2] = pn[kk * G3 + 512];
    }
    float4 a0 = As4[k4 * 32 + ty * 4 + 0];
    float4 a1 = As4[k4 * 32 + ty * 4 + 1];
    float4 a2 = As4[k4 * 32 + ty * 4 + 2];
    float4 a3 = As4[k4 * 32 + ty * 4 + 3];
#pragma unroll
    for (int kk = 0; kk < 4; ++kk) {
      float br = bc[kk*3], bz = bc[kk*3+1], bnn = bc[kk*3+2];
      float e0 = ((const float*)&a0)[kk];
      float e1 = ((const float*)&a1)[kk];
      float e2 = ((const float*)&a2)[kk];
      float e3 = ((const float*)&a3)[kk];
      acc[0][0] += e0 * br; acc[0][1] += e0 * bz; acc[0][2] += e0 * bnn;
      acc[1][0] += e1 * br; acc[1][1] += e1 * bz; acc[1][2] += e1 * bnn;
      acc[2][0] += e2 * br; acc[2][1] += e2 * bz; acc[2][2] += e2 * bnn;
      acc[3][0] += e3 * br; acc[3][1] += e3 * bz; acc[3][2] += e3 * bnn;
    }
#pragma unroll
    for (int q = 0; q < 12; ++q) bc[q] = bn_[q];
  }

#pragma unroll
  for (int r = 0; r < 4; ++r) {
    int row = m0 + ty * 4 + r;
    float xw[3];
#pragma unroll
    for (int g = 0; g < 3; ++g) {
      const float* wi = Wih + (size_t)(g * 256 + j) * D_FEAT;
      float s = bih[g * 256 + j];
#pragma unroll
      for (int i = 0; i < D_FEAT; ++i) s += xs[ty * 4 + r][i] * wi[i];
      xw[g] = s;
    }
    float ghr = acc[r][0] + bhh[j];
    float ghz = acc[r][1] + bhh[256 + j];
    float ghn = acc[r][2] + bhh[512 + j];
    float rr = sigmoidf_(xw[0] + ghr);
    float zz = sigmoidf_(xw[1] + ghz);
    float nn = tanhf(xw[2] + rr * ghn);
    float hold = hprev[(size_t)row * HID + j];
    hout[(size_t)row * HID + j] = (1.f - zz) * nn + zz * hold;
  }
}

// ---------------------------------------------------------------- GRU layer 1 step
__global__ __launch_bounds__(256, 2)
void gru1_step(const float* __restrict__ xin, const float* __restrict__ hprev,
               float* __restrict__ hout, const float* __restrict__ WTcat,
               const float* __restrict__ bih, const float* __restrict__ bhh)
{
  __shared__ float4 As4[128 * 32];   // [k4][m]
  const int tx = threadIdx.x, ty = threadIdx.y;
  const int tid = ty * 32 + tx;
  const int j0 = blockIdx.x * 32, m0 = blockIdx.y * 32;

  for (int c = tid; c < 4096; c += 256) {
    int k4 = c & 127, m = c >> 7;
    const float* src = (k4 < 64) ? (xin + (size_t)(m0 + m) * HID + k4 * 4)
                                 : (hprev + (size_t)(m0 + m) * HID + (k4 - 64) * 4);
    As4[k4 * 32 + m] = *(const float4*)src;
  }
  __syncthreads();

  float ar[4] = {0,0,0,0}, az[4] = {0,0,0,0}, axn[4] = {0,0,0,0}, ahn[4] = {0,0,0,0};
  const int j = j0 + tx;
  const float* Wb = WTcat + j;

  float bc[12], bn_[12];
#pragma unroll
  for (int kk = 0; kk < 4; ++kk) {
    bc[kk*3+0] = Wb[(size_t)kk * G3];
    bc[kk*3+1] = Wb[(size_t)kk * G3 + 256];
    bc[kk*3+2] = Wb[(size_t)kk * G3 + 512];
  }
  // first half: k4 0..63 (x-input part) — prefetch flows into row 64 seamlessly
  for (int k4 = 0; k4 < 64; ++k4) {
    const float* pn = Wb + (size_t)(k4 + 1) * 4 * G3;   // rows 1..64, all valid
#pragma unroll
    for (int kk = 0; kk < 4; ++kk) {
      bn_[kk*3+0] = pn[kk * G3];
      bn_[kk*3+1] = pn[kk * G3 + 256];
      bn_[kk*3+2] = pn[kk * G3 + 512];
    }
    float4 a0 = As4[k4 * 32 + ty * 4 + 0];
    float4 a1 = As4[k4 * 32 + ty * 4 + 1];
    float4 a2 = As4[k4 * 32 + ty * 4 + 2];
    float4 a3 = As4[k4 * 32 + ty * 4 + 3];
#pragma unroll
    for (int kk = 0; kk < 4; ++kk) {
      float br = bc[kk*3], bz = bc[kk*3+1], bnn = bc[kk*3+2];
      float e0 = ((const float*)&a0)[kk];
      float e1 = ((const float*)&a1)[kk];
      float e2 = ((const float*)&a2)[kk];
      float e3 = ((const float*)&a3)[kk];
      ar[0] += e0 * br; az[0] += e0 * bz; axn[0] += e0 * bnn;
      ar[1] += e1 * br; az[1] += e1 * bz; axn[1] += e1 * bnn;
      ar[2] += e2 * br; az[2] += e2 * bz; axn[2] += e2 * bnn;
      ar[3] += e3 * br; az[3] += e3 * bz; axn[3] += e3 * bnn;
    }
#pragma unroll
    for (int q = 0; q < 12; ++q) bc[q] = bn_[q];
  }
  // second half: k4 64..127 (h-part)
  for (int k4 = 64; k4 < 128; ++k4) {
    int nk4 = (k4 + 1) & 127;           // wrap at end (unused)
    const float* pn = Wb + (size_t)nk4 * 4 * G3;
#pragma unroll
    for (int kk = 0; kk < 4; ++kk) {
      bn_[kk*3+0] = pn[kk * G3];
      bn_[kk*3+1] = pn[kk * G3 + 256];
      bn_[kk*3+2] = pn[kk * G3 + 512];
    }
    float4 a0 = As4[k4 * 32 + ty * 4 + 0];
    float4 a1 = As4[k4 * 32 + ty * 4 + 1];
    float4 a2 = As4[k4 * 32 + ty * 4 + 2];
    float4 a3 = As4[k4 * 32 + ty * 4 + 3];
#pragma unroll
    for (int kk = 0; kk < 4; ++kk) {
      float br = bc[kk*3], bz = bc[kk*3+1], bnn = bc[kk*3+2];
      float e0 = ((const float*)&a0)[kk];
      float e1 = ((const float*)&a1)[kk];
      float e2 = ((const float*)&a2)[kk];
      float e3 = ((const float*)&a3)[kk];
      ar[0] += e0 * br; az[0] += e0 * bz; ahn[0] += e0 * bnn;
      ar[1] += e1 * br; az[1] += e1 * bz; ahn[1] += e1 * bnn;
      ar[2] += e2 * br; az[2] += e2 * bz; ahn[2] += e2 * bnn;
      ar[3] += e3 * br; az[3] += e3 * bz; ahn[3] += e3 * bnn;
    }
#pragma unroll
    for (int q = 0; q < 12; ++q) bc[q] = bn_[q];
  }

#pragma unroll
  for (int r = 0; r < 4; ++r) {
    int row = m0 + ty * 4 + r;
    float rr = sigmoidf_(ar[r] + bih[j] + bhh[j]);
    float zz = sigmoidf_(az[r] + bih[256 + j] + bhh[256 + j]);
    float nn = tanhf((axn[r] + bih[512 + j]) + rr * (ahn[r] + bhh[512 + j]));
    float hold = hprev[(size_t)row * HID + j];
    hout[(size_t)row * HID + j] = (1.f - zz) * nn + zz * hold;
  }
}

// ---------------------------------------------------------------- generic GEMM
__global__ __launch_bounds__(256, 2)
void gemm_act(const float* __restrict__ A, const int* __restrict__ rowsrc,
              const float* __restrict__ WT, const float* __restrict__ bias,
              float* __restrict__ C, int M, int N, int K, int act)
{
  __shared__ float4 As4[128 * 32];
  const int tx = threadIdx.x, ty = threadIdx.y;
  const int tid = ty * 32 + tx;
  const int n0 = blockIdx.x * 32, m0 = blockIdx.y * 32;
  const int K4 = K >> 2;

  for (int c = tid; c < K4 * 32; c += 256) {
    int k4 = c % K4, m = c / K4;
    int row = m0 + m;
    if (rowsrc) row = rowsrc[row];
    As4[k4 * 32 + m] = *(const float4*)(A + (size_t)row * K + k4 * 4);
  }
  __syncthreads();

  float acc[4] = {0,0,0,0};
  const int n = n0 + tx;
  const float* pb = WT + n;

  float bc[4], bn_[4];
#pragma unroll
  for (int kk = 0; kk < 4; ++kk) bc[kk] = pb[(size_t)kk * N];
  for (int k4 = 0; k4 < K4; ++k4) {
    int nk4 = (k4 + 1 < K4) ? (k4 + 1) : 0;
    const float* pn = pb + (size_t)nk4 * 4 * N;
#pragma unroll
    for (int kk = 0; kk < 4; ++kk) bn_[kk] = pn[(size_t)kk * N];
    float4 a0 = As4[k4 * 32 + ty * 4 + 0];
    float4 a1 = As4[k4 * 32 + ty * 4 + 1];
    float4 a2 = As4[k4 * 32 + ty * 4 + 2];
    float4 a3 = As4[k4 * 32 + ty * 4 + 3];
#pragma unroll
    for (int kk = 0; kk < 4; ++kk) {
      float b = bc[kk];
      acc[0] += ((const float*)&a0)[kk] * b;
      acc[1] += ((const float*)&a1)[kk] * b;
      acc[2] += ((const float*)&a2)[kk] * b;
      acc[3] += ((const float*)&a3)[kk] * b;
    }
#pragma unroll
    for (int q = 0; q < 4; ++q) bc[q] = bn_[q];
  }
  float bb = bias ? bias[n] : 0.f;
#pragma unroll
  for (int r = 0; r < 4; ++r) {
    float v = acc[r] + bb;
    if (act) v = (v >= 0.f) ? v : 0.01f * v;
    C[(size_t)(m0 + ty * 4 + r) * N + n] = v;
  }
}

// ---------------------------------------------------------------- small stages
__global__ void mbday_part(const float* __restrict__ mbf, float* __restrict__ part) {
  int d = blockIdx.x, sl = blockIdx.y, c = threadIdx.x;
  float s = 0.f;
  int base = d * 512 + sl * 64;
  for (int st = 0; st < 64; ++st) s += mbf[(size_t)(base + st) * 256 + c];
  part[(size_t)(d * 8 + sl) * 256 + c] = s;
}

__global__ void mbday_fin(const float* __restrict__ part, float* __restrict__ mbday) {
  int d = blockIdx.x, c = threadIdx.x;
  float s = 0.f;
#pragma unroll
  for (int p = 0; p < 8; ++p) s += part[(size_t)(d * 8 + p) * 256 + c];
  mbday[d * 256 + c] = s * (1.0f / 512.0f);
}

__global__ void daytopk_kernel(const float* __restrict__ mbday, const float* __restrict__ thd,
                               int* __restrict__ dayidx) {
  __shared__ float mbs[256];
  __shared__ float sim[256];
  __shared__ float red[256];
  __shared__ int   redi[256];
  const int d = blockIdx.x, t = threadIdx.x;
  mbs[t] = mbday[d * 256 + t];
  __syncthreads();
  red[t] = mbs[t] * mbs[t];
  __syncthreads();
  for (int o = 128; o; o >>= 1) { if (t < o) red[t] += red[t + o]; __syncthreads(); }
  float xn = sqrtf(red[0]);
  float v = -INFINITY;
  if (t < 240) {
    float dot = 0.f, yn2 = 0.f;
    for (int k = 0; k < 256; ++k) {
      float y = thd[t * 256 + k];
      dot += mbs[k] * y;
      yn2 += y * y;
    }
    float den = xn * sqrtf(yn2);
    v = (den > 0.f) ? dot / den : 0.f;
  }
  sim[t] = v;
  __syncthreads();
  for (int it = 0; it < 10; ++it) {
    red[t] = sim[t]; redi[t] = t;
    __syncthreads();
    for (int o = 128; o; o >>= 1) {
      if (t < o) {
        if (red[t + o] > red[t] || (red[t + o] == red[t] && redi[t + o] < redi[t])) {
          red[t] = red[t + o]; redi[t] = redi[t + o];
        }
      }
      __syncthreads();
    }
    if (t == 0) { int bi = redi[0]; dayidx[d * 10 + it] = bi; sim[bi] = -INFINITY; }
    __syncthreads();
  }
}

__global__ void rowsrc_kernel(const int* __restrict__ dayidx, int* __restrict__ rowsrc) {
  int r = blockIdx.x * 256 + threadIdx.x;
  if (r < NSAMP) rowsrc[r] = dayidx[r >> 9] * 512 + (r & 511);
}

__global__ void rownorm_kernel(const float* __restrict__ X, float* __restrict__ out, int rows) {
  int w = threadIdx.x >> 6;
  int lane = threadIdx.x & 63;
  int row = blockIdx.x * 4 + w;
  if (row >= rows) return;
  float4 x = *(const float4*)(X + (size_t)row * 256 + lane * 4);
  float s = x.x * x.x + x.y * x.y + x.z * x.z + x.w * x.w;
#pragma unroll
  for (int o = 32; o; o >>= 1) s += __shfl_down(s, o, 64);
  if (lane == 0) out[row] = sqrtf(s);
}

__global__ void qnorm_kernel(float* __restrict__ q, const float* __restrict__ qn) {
  int i = blockIdx.x * 256 + threadIdx.x;
  int row = i >> 8;
  float n = qn[row];
  q[i] = (n > 0.f) ? q[i] / n : 0.f;
}

__global__ void khT_kernel(const float* __restrict__ kh, const float* __restrict__ khn,
                           float* __restrict__ khT) {
  __shared__ float tile[32][33];
  int jb = blockIdx.x * 32;
  int kb = blockIdx.y * 32;
  int tx = threadIdx.x & 31, tyy = threadIdx.x >> 5;
  for (int rr = tyy; rr < 32; rr += 8) {
    float n = khn[jb + rr];
    float v = kh[(size_t)(jb + rr) * 256 + kb + tx];
    tile[rr][tx] = (n > 0.f) ? v / n : 0.f;
  }
  __syncthreads();
  for (int rr = tyy; rr < 32; rr += 8) {
    khT[(size_t)(kb + rr) * NSAMP + jb + tx] = tile[tx][rr];
  }
}

// ---------------------------------------------------------------- cs GEMM + top-10 (split)
// grid (256 m-tiles, 8 j-splits); each block: 8 q-rows x 2560 cols (5 chunks of 512).
// Writes per-(row,split) top-10 candidates; merge_topk reduces 80 -> 10.
__global__ __launch_bounds__(256, 4)
void csmax_kernel(const float* __restrict__ qh, const float* __restrict__ khT,
                  float* __restrict__ topvp, int* __restrict__ topip)
{
  __shared__ float4 qs[256][2];
  __shared__ float csch[8 * 512];
  const int tid = threadIdx.x;
  const int m0 = blockIdx.x * 8;
  const int split = blockIdx.y;
  {
    int k = tid;
    float4 v0, v1;
    v0.x = qh[(size_t)(m0 + 0) * 256 + k]; v0.y = qh[(size_t)(m0 + 1) * 256 + k];
    v0.z = qh[(size_t)(m0 + 2) * 256 + k]; v0.w = qh[(size_t)(m0 + 3) * 256 + k];
    v1.x = qh[(size_t)(m0 + 4) * 256 + k]; v1.y = qh[(size_t)(m0 + 5) * 256 + k];
    v1.z = qh[(size_t)(m0 + 6) * 256 + k]; v1.w = qh[(size_t)(m0 + 7) * 256 + k];
    qs[k][0] = v0; qs[k][1] = v1;
  }
  __syncthreads();
  const int lane = tid & 63;
  const int wv = tid >> 6;

  float tv0[10], tv1[10];
  int   tj0[10], tj1[10];
  int   tn0 = 0, tn1 = 0;
  float tmv0 = -INFINITY, tmv1 = -INFINITY;
  int   tmi0 = 0, tmi1 = 0;

  auto process_row = [&](int r, float (&tv)[10], int (&tj)[10], int& tn,
                         float& tmv, int& tmi, int jb) {
    float4 c0 = *(const float4*)&csch[r * 512 + lane * 8];
    float4 c1 = *(const float4*)&csch[r * 512 + lane * 8 + 4];
    float cv[8] = {c0.x, c0.y, c0.z, c0.w, c1.x, c1.y, c1.z, c1.w};
    const int cj0 = jb + lane * 8;
    while (true) {
      float bv = -INFINITY; int bj = 0x7fffffff;
#pragma unroll
      for (int u = 0; u < 8; ++u) {
        if (cv[u] > bv) { bv = cv[u]; bj = cj0 + u; }
      }
#pragma unroll
      for (int o = 32; o; o >>= 1) {
        float ov = __shfl_down(bv, o, 64);
        int   oj = __shfl_down(bj, o, 64);
        if (ov > bv || (ov == bv && oj < bj)) { bv = ov; bj = oj; }
      }
      bv = __shfl(bv, 0, 64); bj = __shfl(bj, 0, 64);
      bool take;
      if (tn < 10) take = true;
      else take = (bv > tmv) || (bv == tmv && bj < tmi);
      if (!take) break;
      if (tn < 10) {
#pragma unroll
        for (int s = 0; s < 10; ++s) if (s == tn) { tv[s] = bv; tj[s] = bj; }
        tn++;
        if (tn == 10) {
          float mv = tv[0]; int mi = tj[0];
#pragma unroll
          for (int s = 1; s < 10; ++s) {
            bool w = (tv[s] < mv) || (tv[s] == mv && tj[s] > mi);
            if (w) { mv = tv[s]; mi = tj[s]; }
          }
          tmv = mv; tmi = mi;
        }
      } else {
        int ms = 0; float mv = tv[0]; int mi = tj[0];
#pragma unroll
        for (int s = 1; s < 10; ++s) {
          bool w = (tv[s] < mv) || (tv[s] == mv && tj[s] > mi);
          if (w) { ms = s; mv = tv[s]; mi = tj[s]; }
        }
#pragma unroll
        for (int s = 0; s < 10; ++s) if (s == ms) { tv[s] = bv; tj[s] = bj; }
        mv = tv[0]; mi = tj[0];
#pragma unroll
        for (int s = 1; s < 10; ++s) {
          bool w = (tv[s] < mv) || (tv[s] == mv && tj[s] > mi);
          if (w) { mv = tv[s]; mi = tj[s]; }
        }
        tmv = mv; tmi = mi;
      }
#pragma unroll
      for (int u = 0; u < 8; ++u) if (cj0 + u == bj) cv[u] = -INFINITY;
    }
  };

  for (int ci = 0; ci < 5; ++ci) {
    const int ch = split * 5 + ci;
    const int jb = ch * 512;
    float acc[8][2];
#pragma unroll
    for (int r = 0; r < 8; ++r) { acc[r][0] = 0.f; acc[r][1] = 0.f; }
    const float* kp = khT + jb + tid;

    float b0c[4], b1c[4], b0n[4], b1n[4];
#pragma unroll
    for (int kk = 0; kk < 4; ++kk) {
      b0c[kk] = kp[(size_t)kk * NSAMP];
      b1c[kk] = kp[(size_t)kk * NSAMP + 256];
    }
    for (int k4 = 0; k4 < 64; ++k4) {
      int nk4 = (k4 + 1) & 63;
      const float* pn = kp + (size_t)nk4 * 4 * NSAMP;
#pragma unroll
      for (int kk = 0; kk < 4; ++kk) {
        b0n[kk] = pn[(size_t)kk * NSAMP];
        b1n[kk] = pn[(size_t)kk * NSAMP + 256];
      }
#pragma unroll
      for (int kk = 0; kk < 4; ++kk) {
        float4 qa = qs[k4 * 4 + kk][0];
        float4 qb = qs[k4 * 4 + kk][1];
        float b0 = b0c[kk], b1 = b1c[kk];
        acc[0][0] += qa.x * b0; acc[1][0] += qa.y * b0; acc[2][0] += qa.z * b0; acc[3][0] += qa.w * b0;
        acc[4][0] += qb.x * b0; acc[5][0] += qb.y * b0; acc[6][0] += qb.z * b0; acc[7][0] += qb.w * b0;
        acc[0][1] += qa.x * b1; acc[1][1] += qa.y * b1; acc[2][1] += qa.z * b1; acc[3][1] += qa.w * b1;
        acc[4][1] += qb.x * b1; acc[5][1] += qb.y * b1; acc[6][1] += qb.z * b1; acc[7][1] += qb.w * b1;
      }
#pragma unroll
      for (int q = 0; q < 4; ++q) { b0c[q] = b0n[q]; b1c[q] = b1n[q]; }
    }
    __syncthreads();
#pragma unroll
    for (int r = 0; r < 8; ++r) {
      csch[r * 512 + tid] = acc[r][0];
      csch[r * 512 + 256 + tid] = acc[r][1];
    }
    __syncthreads();
    process_row(wv,     tv0, tj0, tn0, tmv0, tmi0, jb);
    process_row(wv + 4, tv1, tj1, tn1, tmv1, tmi1, jb);
  }
  __syncthreads();

  if (lane == 0) {
    int row0 = m0 + wv;
#pragma unroll
    for (int s = 0; s < 10; ++s) {
      topvp[(size_t)row0 * 80 + split * 10 + s] = tv0[s];
      topip[(size_t)row0 * 80 + split * 10 + s] = tj0[s];
    }
    int row1 = m0 + wv + 4;
#pragma unroll
    for (int s = 0; s < 10; ++s) {
      topvp[(size_t)row1 * 80 + split * 10 + s] = tv1[s];
      topip[(size_t)row1 * 80 + split * 10 + s] = tj1[s];
    }
  }
}

// merge 8 splits x 10 candidates -> global top-10 per row (value desc, idx asc)
__global__ void merge_topk(const float* __restrict__ topvp, const int* __restrict__ topip,
                           float* __restrict__ topv, int* __restrict__ topi)
{
  const int wv = threadIdx.x >> 6;
  const int lane = threadIdx.x & 63;
  const int row = blockIdx.x * 4 + wv;
  float v0 = topvp[(size_t)row * 80 + lane];
  int   i0 = topip[(size_t)row * 80 + lane];
  float v1 = (lane < 16) ? topvp[(size_t)row * 80 + 64 + lane] : -INFINITY;
  int   i1 = (lane < 16) ? topip[(size_t)row * 80 + 64 + lane] : 0x7fffffff;
  for (int s = 0; s < 10; ++s) {
    float bv = v0; int bj = i0;
    if (v1 > bv || (v1 == bv && i1 < bj)) { bv = v1; bj = i1; }
#pragma unroll
    for (int o = 1; o < 64; o <<= 1) {
      float ov = __shfl_xor(bv, o, 64);
      int   oj = __shfl_xor(bj, o, 64);
      if (ov > bv || (ov == bv && oj < bj)) { bv = ov; bj = oj; }
    }
    if (lane == 0) { topv[row * 10 + s] = bv; topi[row * 10 + s] = bj; }
    if (i0 == bj) { v0 = -INFINITY; i0 = 0x7fffffff; }
    if (i1 == bj) { v1 = -INFINITY; i1 = 0x7fffffff; }
  }
}

// ---------------------------------------------------------------- final: agg + fc
__global__ void final_kernel(const float* __restrict__ mb, const float* __restrict__ kh,
                             const float* __restrict__ topv, const int* __restrict__ topi,
                             const float* __restrict__ fcW, const float* __restrict__ fcb,
                             float* __restrict__ y)
{
  __shared__ float red[256];
  int n = blockIdx.x, c = threadIdx.x;
  float agg = 0.f;
#pragma unroll
  for (int k = 0; k < 10; ++k) {
    float w = topv[n * 10 + k] / 10.0f;
    int idx = topi[n * 10 + k];
    agg += w * kh[(size_t)idx * 256 + c];
  }
  float val = fcW[c] * mb[(size_t)n * 256 + c] + fcW[256 + c] * agg;
  red[c] = val;
  __syncthreads();
  for (int o = 128; o; o >>= 1) { if (c < o) red[c] += red[c + o]; __syncthreads(); }
  if (c == 0) y[n] = red[0] + fcb[0];
}

// ---------------------------------------------------------------- launch
extern "C" void kernel_launch(void* const* d_in, const int* in_sizes, int n_in,
                              void* d_out, int out_size, void* d_ws, size_t ws_size,
                              hipStream_t stream)
{
  const float* inp    = (const float*)d_in[0];
  const float* trainh = (const float*)d_in[1];
  const float* thd    = (const float*)d_in[2];
  const float* Wih0   = (const float*)d_in[3];
  const float* Whh0   = (const float*)d_in[4];
  const float* bih0   = (const float*)d_in[5];
  const float* bhh0   = (const float*)d_in[6];
  const float* Wih1   = (const float*)d_in[7];
  const float* Whh1   = (const float*)d_in[8];
  const float* bih1   = (const float*)d_in[9];
  const float* bhh1   = (const float*)d_in[10];
  const float* lin0W  = (const float*)d_in[11];
  const float* lin0b  = (const float*)d_in[12];
  const float* lin1W  = (const float*)d_in[13];
  const float* lin1b  = (const float*)d_in[14];
  const float* lin2W  = (const float*)d_in[15];
  const float* lin2b  = (const float*)d_in[16];
  const float* p1W    = (const float*)d_in[17];
  const float* p2W    = (const float*)d_in[18];
  const float* fcW    = (const float*)d_in[19];
  const float* fcb    = (const float*)d_in[20];

  float* ws = (float*)d_ws;
  float* WT_hh0 = ws + 0;          // 256x768
  float* WTcat  = ws + 196608;     // 512x768
  float* WT_l0  = ws + 589824;     // 256x512
  float* WT_l1  = ws + 720896;     // 512x512
  float* WT_l2  = ws + 983040;     // 512x256
  float* WT_p1  = ws + 1114112;    // 256x256
  float* WT_p2  = ws + 1179648;    // 256x256
  float* h0a    = ws + 1245184;
  float* h0b    = ws + 1769472;
  float* h1a    = ws + 2293760;
  float* h1b    = ws + 2818048;
  float* mb1    = ws + 3342336;    // 2048x512 (dead after lin1 -> reused for candidates)
  float* mb2    = ws + 4390912;    // 2048x512 (dead after lin2 -> reused for mbday partials)
  float* mbf    = ws + 5439488;    // 2048x256
  float* mbday  = ws + 5963776;    // 4x256
  float* qbuf   = ws + 5964800;    // 2048x256
  float* kh     = ws + 6489088;    // 20480x256
  float* khT    = ws + 11731968;   // 256x20480 (normalized)
  float* khn    = ws + 16974848;   // 20480
  float* qn     = ws + 16995328;   // 2048
  float* topv   = ws + 16997376;   // 2048x10
  int*   dayidx = (int*)(ws + 17017856); // 40
  int*   rowsrc = (int*)(ws + 17017920); // 20480
  int*   topi   = (int*)(ws + 17038400); // 2048x10
  // reused regions:
  float* topvp  = mb1;                       // 2048x80
  int*   topip  = (int*)(mb1 + 163840);      // 2048x80
  float* mbpart = mb2;                       // 4x8x256

  PrepArgs pa;
  pa.src[0] = Whh0;  pa.dst[0] = WT_hh0; pa.N[0] = 768; pa.K[0] = 256; pa.ro[0] = 0;
  pa.src[1] = Wih1;  pa.dst[1] = WTcat;  pa.N[1] = 768; pa.K[1] = 256; pa.ro[1] = 0;
  pa.src[2] = Whh1;  pa.dst[2] = WTcat;  pa.N[2] = 768; pa.K[2] = 256; pa.ro[2] = 256;
  pa.src[3] = lin0W; pa.dst[3] = WT_l0;  pa.N[3] = 512; pa.K[3] = 256; pa.ro[3] = 0;
  pa.src[4] = lin1W; pa.dst[4] = WT_l1;  pa.N[4] = 512; pa.K[4] = 512; pa.ro[4] = 0;
  pa.src[5] = lin2W; pa.dst[5] = WT_l2;  pa.N[5] = 256; pa.K[5] = 512; pa.ro[5] = 0;
  pa.src[6] = p1W;   pa.dst[6] = WT_p1;  pa.N[6] = 256; pa.K[6] = 256; pa.ro[6] = 0;
  pa.src[7] = p2W;   pa.dst[7] = WT_p2;  pa.N[7] = 256; pa.K[7] = 256; pa.ro[7] = 0;
  prep_weights<<<dim3(64, 8), dim3(256), 0, stream>>>(pa);

  hipMemsetAsync(h0a, 0, (size_t)NROW * HID * 4, stream);
  hipMemsetAsync(h1a, 0, (size_t)NROW * HID * 4, stream);

  float *h0c = h0a, *h0n = h0b, *h1c = h1a, *h1n = h1b;
  for (int t = 0; t < T_SEQ; ++t) {
    gru0_step<<<dim3(8, 64), dim3(32, 8), 0, stream>>>(h0c, h0n, inp, WT_hh0, Wih0, bih0, bhh0, t);
    gru1_step<<<dim3(8, 64), dim3(32, 8), 0, stream>>>(h0n, h1c, h1n, WTcat, bih1, bhh1);
    float* tmp;
    tmp = h0c; h0c = h0n; h0n = tmp;
    tmp = h1c; h1c = h1n; h1n = tmp;
  }

  gemm_act<<<dim3(16, 64), dim3(32, 8), 0, stream>>>(h1c, nullptr, WT_l0, lin0b, mb1, 2048, 512, 256, 1);
  gemm_act<<<dim3(16, 64), dim3(32, 8), 0, stream>>>(mb1, nullptr, WT_l1, lin1b, mb2, 2048, 512, 512, 1);
  gemm_act<<<dim3(8, 64),  dim3(32, 8), 0, stream>>>(mb2, nullptr, WT_l2, lin2b, mbf, 2048, 256, 512, 1);

  mbday_part<<<dim3(4, 8), 256, 0, stream>>>(mbf, mbpart);
  mbday_fin<<<4, 256, 0, stream>>>(mbpart, mbday);
  daytopk_kernel<<<4, 256, 0, stream>>>(mbday, thd, dayidx);
  rowsrc_kernel<<<80, 256, 0, stream>>>(dayidx, rowsrc);

  gemm_act<<<dim3(8, 640), dim3(32, 8), 0, stream>>>(trainh, rowsrc, WT_p2, nullptr, kh, 20480, 256, 256, 0);
  gemm_act<<<dim3(8, 64),  dim3(32, 8), 0, stream>>>(mbf, nullptr, WT_p1, nullptr, qbuf, 2048, 256, 256, 0);

  rownorm_kernel<<<5120, 256, 0, stream>>>(kh, khn, 20480);
  rownorm_kernel<<<512, 256, 0, stream>>>(qbuf, qn, 2048);
  qnorm_kernel<<<2048, 256, 0, stream>>>(qbuf, qn);
  khT_kernel<<<dim3(640, 8), 256, 0, stream>>>(kh, khn, khT);

  csmax_kernel<<<dim3(256, 8), 256, 0, stream>>>(qbuf, khT, topvp, topip);
  merge_topk<<<512, 256, 0, stream>>>(topvp, topip, topv, topi);
  final_kernel<<<2048, 256, 0, stream>>>(mbf, kh, topv, topi, fcW, fcb, (float*)d_out);

  (void)in_sizes; (void)n_in; (void)out_size; (void)ws_size;
}